// Round 14
// baseline (658.882 us; speedup 1.0000x reference)
//
#include <hip/hip_runtime.h>
#include <math.h>

#define B_  32
#define T_  512
#define S_  256
#define D_  256
#define H_  8
#define HD_ 32
#define FF_ 1024
#define ED_ 768
#define L_  4
#define BT_ (B_*T_)   // 16384
#define BS_ (B_*S_)   // 8192

typedef __bf16 bf16x8_t __attribute__((ext_vector_type(8)));
typedef __bf16 bf16x4_t __attribute__((ext_vector_type(4)));
typedef float  f32x4_t  __attribute__((ext_vector_type(4)));

__device__ __forceinline__ float gelu_f(float v) {
  return 0.5f * v * (1.f + erff(v * 0.7071067811865476f));
}

// async global->LDS, 16B per lane; LDS dest = wave-uniform base + lane*16
__device__ __forceinline__ void gl16(const __bf16* gsrc, __bf16* ldst) {
  __builtin_amdgcn_global_load_lds(
      (const __attribute__((address_space(1))) unsigned int*)gsrc,
      (__attribute__((address_space(3))) unsigned int*)ldst, 16, 0, 0);
}

// ---------------- embed: x = tgt*W_emb + b_emb + pos_encoding ----------------
__global__ __launch_bounds__(256)
void embed_kernel(const float* __restrict__ tgt, const float* __restrict__ Wemb,
                  const float* __restrict__ bemb, float* __restrict__ x,
                  __bf16* __restrict__ xbf) {
  int i = blockIdx.x * 256 + threadIdx.x;
  int d  = i & (D_ - 1);
  int bt = i >> 8;
  int t  = bt & (T_ - 1);
  int p  = d >> 1;
  float div = expf((float)(2 * p) * (-9.210340371976184f / (float)D_));
  float arg = (float)t * div;
  float pe = (d & 1) ? cosf(arg) : sinf(arg);
  float v = tgt[bt] * Wemb[d] + bemb[d] + pe;
  x[i] = v;
  xbf[i] = (__bf16)v;
}

// ---------------- fp32 -> bf16 bulk convert ----------------------------------
__global__ __launch_bounds__(256)
void cvt_bf16_kernel(const float* __restrict__ in, __bf16* __restrict__ out) {
  int i = (blockIdx.x * 256 + threadIdx.x) * 4;
  float4 v = *(const float4*)(in + i);
  bf16x4_t o;
  o[0] = (__bf16)v.x; o[1] = (__bf16)v.y; o[2] = (__bf16)v.z; o[3] = (__bf16)v.w;
  *(bf16x4_t*)(out + i) = o;
}

// ------------- weight pre-pass: transpose [K][N] fp32 -> [N][K] bf16 ---------
struct TD { const float* src; size_t dst; int K, N, nb; size_t lstride; };
struct TDs { TD d[12]; };

__global__ __launch_bounds__(256)
void transpose_cvt_kernel(TDs a, __bf16* __restrict__ wt) {
  __shared__ float tile[32][33];
  TD t = a.d[blockIdx.y];
  const int kt = t.K >> 5, nt = t.N >> 5;
  const int per = kt * nt, tot = per * t.nb;
  const int id = blockIdx.x;
  if (id >= tot) return;
  const int b = id / per;
  const int r2 = id - b * per;
  const int kti = r2 / nt;
  const int nti = r2 - kti * nt;
  const int c = threadIdx.x & 31, r0 = threadIdx.x >> 5;
  const float* src = t.src + (size_t)b * t.K * t.N;
  __bf16* dst = wt + t.dst + (size_t)b * t.lstride;
#pragma unroll
  for (int j = 0; j < 4; ++j) {
    int rr = r0 + j * 8;
    tile[rr][c] = src[(size_t)(kti * 32 + rr) * t.N + nti * 32 + c];
  }
  __syncthreads();
#pragma unroll
  for (int j = 0; j < 4; ++j) {
    int rr = r0 + j * 8;
    dst[(size_t)(nti * 32 + rr) * t.K + kti * 32 + c] = (__bf16)tile[c][rr];
  }
}

// ---------------- concat biases: [L][768] self-qkv, then [L][512] cross-kv ---
__global__ __launch_bounds__(256)
void bias_concat_kernel(const float* __restrict__ bq_s, const float* __restrict__ bk_s,
                        const float* __restrict__ bv_s, const float* __restrict__ bk_c,
                        const float* __restrict__ bv_c, float* __restrict__ dst) {
  int idx = blockIdx.x * 256 + threadIdx.x;
  if (idx >= 5120) return;
  if (idx < 3072) {
    int l = idx / 768, c = idx - l * 768;
    float v = (c < 256) ? bq_s[l * 256 + c]
            : (c < 512) ? bk_s[l * 256 + c - 256]
                        : bv_s[l * 256 + c - 512];
    dst[idx] = v;
  } else {
    int j = idx - 3072;
    int l = j / 512, c = j - l * 512;
    float v = (c < 256) ? bk_c[l * 256 + c] : bv_c[l * 256 + c - 256];
    dst[idx] = v;
  }
}

// ------------- bf16 MFMA GEMM, tile 128x64 ----------------------------------
template<int ACT, int OBF>
__global__ __launch_bounds__(256, 3)
void gemm_bf(const __bf16* __restrict__ A, const __bf16* __restrict__ Bt,
             const float* __restrict__ bias, void* __restrict__ Cv,
             int N, int K, int nN, int ppx) {
  __shared__ __bf16 As[128 * 64];
  __shared__ __bf16 Bs[64 * 64];
  const int tid = threadIdx.x, lane = tid & 63, wv = tid >> 6;
  const int wm = (wv & 1) * 64, wn = (wv >> 1) * 32;
  const int ln15 = lane & 15, kgrp = lane >> 4;
  const int xcd = blockIdx.x & 7, j = blockIdx.x >> 3;
  const int bm = (xcd * ppx + j / nN) * 128;
  const int bn = (j % nN) * 64;

  const int r8 = lane >> 3;
  const int scol = (lane & 7) ^ r8;
  const __bf16* a_g = A  + (size_t)(bm + wv * 32 + r8) * K + scol * 8;
  const __bf16* b_g = Bt + (size_t)(bn + wv * 16 + r8) * K + scol * 8;
  __bf16* a_l = As + wv * 2048;
  __bf16* b_l = Bs + wv * 1024;

  const int xk0 = kgrp ^ (ln15 & 7);
  const int xk1 = (4 + kgrp) ^ (ln15 & 7);

  f32x4_t acc[4][2];
#pragma unroll
  for (int mi = 0; mi < 4; ++mi)
#pragma unroll
    for (int ni = 0; ni < 2; ++ni) acc[mi][ni] = (f32x4_t){0.f, 0.f, 0.f, 0.f};

  for (int k0 = 0; k0 < K; k0 += 64) {
    gl16(a_g + k0,                a_l);
    gl16(a_g + k0 + (size_t)8*K,  a_l + 512);
    gl16(a_g + k0 + (size_t)16*K, a_l + 1024);
    gl16(a_g + k0 + (size_t)24*K, a_l + 1536);
    gl16(b_g + k0,                b_l);
    gl16(b_g + k0 + (size_t)8*K,  b_l + 512);
    __syncthreads();

#pragma unroll
    for (int kk = 0; kk < 2; ++kk) {
      const int xk = kk ? xk1 : xk0;
      bf16x8_t b0 = *(const bf16x8_t*)(Bs + ((wn + ln15) * 8 + xk) * 8);
      bf16x8_t b1 = *(const bf16x8_t*)(Bs + ((wn + 16 + ln15) * 8 + xk) * 8);
#pragma unroll
      for (int mi = 0; mi < 4; ++mi) {
        bf16x8_t af = *(const bf16x8_t*)(As + ((wm + mi * 16 + ln15) * 8 + xk) * 8);
        acc[mi][0] = __builtin_amdgcn_mfma_f32_16x16x32_bf16(af, b0, acc[mi][0], 0, 0, 0);
        acc[mi][1] = __builtin_amdgcn_mfma_f32_16x16x32_bf16(af, b1, acc[mi][1], 0, 0, 0);
      }
    }
    __syncthreads();
  }

#pragma unroll
  for (int mi = 0; mi < 4; ++mi) {
#pragma unroll
    for (int ni = 0; ni < 2; ++ni) {
      const int ocol = bn + wn + ni * 16 + ln15;
      const float bv = bias[ocol];
      const int orow0 = bm + wm + mi * 16 + kgrp * 4;
#pragma unroll
      for (int r = 0; r < 4; ++r) {
        float o = acc[mi][ni][r] + bv;
        if (ACT == 1) o = gelu_f(o);
        if (OBF) ((__bf16*)Cv)[(size_t)(orow0 + r) * N + ocol] = (__bf16)o;
        else     ((float*)Cv)[(size_t)(orow0 + r) * N + ocol] = o;
      }
    }
  }
}

// ------------- bf16 MFMA GEMM, tile 128x128 (wide-N: QKV0, KVall) ------------
template<int ACT, int OBF>
__global__ __launch_bounds__(256, 3)
void gemm_bf2(const __bf16* __restrict__ A, const __bf16* __restrict__ Bt,
              const float* __restrict__ bias, void* __restrict__ Cv,
              int N, int K, int nN, int ppx) {
  __shared__ __bf16 As[128 * 64];
  __shared__ __bf16 Bs[128 * 64];
  const int tid = threadIdx.x, lane = tid & 63, wv = tid >> 6;
  const int wm = (wv & 1) * 64, wn = (wv >> 1) * 64;
  const int ln15 = lane & 15, kgrp = lane >> 4;
  const int xcd = blockIdx.x & 7, j = blockIdx.x >> 3;
  const int bm = (xcd * ppx + j / nN) * 128;
  const int bn = (j % nN) * 128;

  const int r8 = lane >> 3;
  const int scol = (lane & 7) ^ r8;
  const __bf16* a_g = A  + (size_t)(bm + wv * 32 + r8) * K + scol * 8;
  const __bf16* b_g = Bt + (size_t)(bn + wv * 32 + r8) * K + scol * 8;
  __bf16* a_l = As + wv * 2048;
  __bf16* b_l = Bs + wv * 2048;

  const int xk0 = kgrp ^ (ln15 & 7);
  const int xk1 = (4 + kgrp) ^ (ln15 & 7);

  f32x4_t acc[4][4];
#pragma unroll
  for (int mi = 0; mi < 4; ++mi)
#pragma unroll
    for (int ni = 0; ni < 4; ++ni) acc[mi][ni] = (f32x4_t){0.f, 0.f, 0.f, 0.f};

  for (int k0 = 0; k0 < K; k0 += 64) {
    gl16(a_g + k0,                a_l);
    gl16(a_g + k0 + (size_t)8*K,  a_l + 512);
    gl16(a_g + k0 + (size_t)16*K, a_l + 1024);
    gl16(a_g + k0 + (size_t)24*K, a_l + 1536);
    gl16(b_g + k0,                b_l);
    gl16(b_g + k0 + (size_t)8*K,  b_l + 512);
    gl16(b_g + k0 + (size_t)16*K, b_l + 1024);
    gl16(b_g + k0 + (size_t)24*K, b_l + 1536);
    __syncthreads();

#pragma unroll
    for (int kk = 0; kk < 2; ++kk) {
      const int xk = kk ? xk1 : xk0;
      bf16x8_t bfr[4];
#pragma unroll
      for (int ni = 0; ni < 4; ++ni)
        bfr[ni] = *(const bf16x8_t*)(Bs + ((wn + ni * 16 + ln15) * 8 + xk) * 8);
#pragma unroll
      for (int mi = 0; mi < 4; ++mi) {
        bf16x8_t af = *(const bf16x8_t*)(As + ((wm + mi * 16 + ln15) * 8 + xk) * 8);
#pragma unroll
        for (int ni = 0; ni < 4; ++ni)
          acc[mi][ni] = __builtin_amdgcn_mfma_f32_16x16x32_bf16(af, bfr[ni], acc[mi][ni], 0, 0, 0);
      }
    }
    __syncthreads();
  }

#pragma unroll
  for (int mi = 0; mi < 4; ++mi) {
#pragma unroll
    for (int ni = 0; ni < 4; ++ni) {
      const int ocol = bn + wn + ni * 16 + ln15;
      const float bv = bias[ocol];
      const int orow0 = bm + wm + mi * 16 + kgrp * 4;
#pragma unroll
      for (int r = 0; r < 4; ++r) {
        float o = acc[mi][ni][r] + bv;
        if (ACT == 1) o = gelu_f(o);
        if (OBF) ((__bf16*)Cv)[(size_t)(orow0 + r) * N + ocol] = (__bf16)o;
        else     ((float*)Cv)[(size_t)(orow0 + r) * N + ocol] = o;
      }
    }
  }
}

// ------ fused GEMM(32x256) + residual + LN [+ next GEMM from LDS xnorm] -----
// R14: same 512 blocks / same staging as R13, but 512 threads = 8 waves, each
// wave owning a 32-col N-slice (acc[2][2], 8 MFMA/step). 16 waves/CU (4/SIMD)
// doubles TLP over R13's 8 waves/CU -- targets the barrier-latency bound that
// R8-R12's block-level variants couldn't move (MfmaUtil stuck at 7.5-8%).
template<int NEXT_N, int NACT, int WXBF>
__global__ __launch_bounds__(512, 4)
void gemm_ln_next(const __bf16* __restrict__ A, const __bf16* __restrict__ Bt,
                  const float* __restrict__ bias, const float* __restrict__ g,
                  const float* __restrict__ bta, float* __restrict__ x,
                  __bf16* __restrict__ xbf, int K, int ppx,
                  const __bf16* __restrict__ Wn, const float* __restrict__ bn,
                  __bf16* __restrict__ outn) {
  __shared__ __bf16 As[32 * 64];      // 4 KB
  __shared__ __bf16 Bs[256 * 64];     // 32 KB (phase-1 B / phase-2 W)
  __shared__ __bf16 An[32 * 256];     // 16 KB normalized rows (phase-2 A)
  __shared__ float red[32][16];       // 2 KB (8 waves x {s,q})
  const int tid = threadIdx.x, lane = tid & 63, wv = tid >> 6;   // wv 0..7
  const int wn = wv * 32;                       // per-wave 32-col N slice
  const int ln15 = lane & 15, kgrp = lane >> 4;
  const int xcd = blockIdx.x & 7, j = blockIdx.x >> 3;
  const int bm = (xcd * ppx + j) * 32;

  // staging maps
  const int srA = tid >> 3;                     // 0..63 (A uses tid<256 -> 0..31)
  const int schA = (tid & 7) ^ (srA & 7);       // pre-swizzled source chunk
  const __bf16* a_g = A  + (size_t)(bm + srA) * K + schA * 8;
  const __bf16* b_g = Bt + (size_t)srA * K + schA * 8;   // rows srA + jj*64

  f32x4_t acc[2][2];
#pragma unroll
  for (int mi = 0; mi < 2; ++mi)
#pragma unroll
    for (int ni = 0; ni < 2; ++ni) acc[mi][ni] = (f32x4_t){0.f, 0.f, 0.f, 0.f};

  // ---- phase 1: y(32x256) = A @ Bt^T ----
  for (int k0 = 0; k0 < K; k0 += 64) {
    if (tid < 256) gl16(a_g + k0, As + wv * 512);
#pragma unroll
    for (int jj = 0; jj < 4; ++jj)
      gl16(b_g + k0 + (size_t)(jj * 64) * K, Bs + jj * 4096 + wv * 512);
    __syncthreads();
#pragma unroll
    for (int kk = 0; kk < 2; ++kk) {
      bf16x8_t bfr[2];
#pragma unroll
      for (int ni = 0; ni < 2; ++ni) {
        const int nl = wn + ni * 16 + ln15;
        bfr[ni] = *(const bf16x8_t*)(Bs + (nl * 8 + ((kk * 4 + kgrp) ^ (nl & 7))) * 8);
      }
#pragma unroll
      for (int mi = 0; mi < 2; ++mi) {
        const int rl = mi * 16 + ln15;
        bf16x8_t af = *(const bf16x8_t*)(As + (rl * 8 + ((kk * 4 + kgrp) ^ (rl & 7))) * 8);
#pragma unroll
        for (int ni = 0; ni < 2; ++ni)
          acc[mi][ni] = __builtin_amdgcn_mfma_f32_16x16x32_bf16(af, bfr[ni], acc[mi][ni], 0, 0, 0);
      }
    }
    __syncthreads();
  }

  // ---- phase-1 epilogue: residual + LN over 256 cols (8-wave reduce) ----
  const int c0 = wn + ln15;
  float bs[2], gg[2], bb[2];
#pragma unroll
  for (int ni = 0; ni < 2; ++ni) {
    bs[ni] = bias[c0 + ni * 16];
    gg[ni] = g[c0 + ni * 16];
    bb[ni] = bta[c0 + ni * 16];
  }
  float v[2][2][4];
#pragma unroll
  for (int mi = 0; mi < 2; ++mi) {
#pragma unroll
    for (int r = 0; r < 4; ++r) {
      const int rl = mi * 16 + kgrp * 4 + r;
      const int row = bm + rl;
      float s = 0.f, q = 0.f;
#pragma unroll
      for (int ni = 0; ni < 2; ++ni) {
        float t = acc[mi][ni][r] + bs[ni] + x[(size_t)row * 256 + c0 + ni * 16];
        v[mi][ni][r] = t; s += t; q += t * t;
      }
      s += __shfl_xor(s, 1); s += __shfl_xor(s, 2);
      s += __shfl_xor(s, 4); s += __shfl_xor(s, 8);
      q += __shfl_xor(q, 1); q += __shfl_xor(q, 2);
      q += __shfl_xor(q, 4); q += __shfl_xor(q, 8);
      if (ln15 == 0) {
        red[rl][wv * 2 + 0] = s;
        red[rl][wv * 2 + 1] = q;
      }
    }
  }
  __syncthreads();
#pragma unroll
  for (int mi = 0; mi < 2; ++mi) {
#pragma unroll
    for (int r = 0; r < 4; ++r) {
      const int rl = mi * 16 + kgrp * 4 + r;
      const int row = bm + rl;
      float ms = 0.f, mq = 0.f;
#pragma unroll
      for (int w8 = 0; w8 < 8; ++w8) { ms += red[rl][w8 * 2]; mq += red[rl][w8 * 2 + 1]; }
      const float mean = ms * (1.f / 256.f);
      const float var  = mq * (1.f / 256.f) - mean * mean;
      const float rstd = rsqrtf(fmaxf(var, 0.f) + 1e-5f);
#pragma unroll
      for (int ni = 0; ni < 2; ++ni) {
        const int c = c0 + ni * 16;
        float o = (v[mi][ni][r] - mean) * rstd * gg[ni] + bb[ni];
        x[(size_t)row * 256 + c] = o;
        __bf16 ob = (__bf16)o;
        if (WXBF) xbf[(size_t)row * 256 + c] = ob;
        if (NEXT_N > 0)
          An[rl * 256 + (((c >> 3) ^ (rl & 7)) << 3) + (c & 7)] = ob;
      }
    }
  }

  // ---- phase 2: outn = xnorm @ Wn^T + bn ----
  if (NEXT_N > 0) {
    for (int pass = 0; pass < NEXT_N / 256; ++pass) {
      const int n0 = pass * 256;
      f32x4_t a2[2][2];
#pragma unroll
      for (int mi = 0; mi < 2; ++mi)
#pragma unroll
        for (int ni = 0; ni < 2; ++ni) a2[mi][ni] = (f32x4_t){0.f, 0.f, 0.f, 0.f};

      for (int k0 = 0; k0 < 256; k0 += 64) {
        const __bf16* wsrc = Wn + (size_t)(n0 + srA) * 256 + k0 + schA * 8;
#pragma unroll
        for (int jj = 0; jj < 4; ++jj)
          gl16(wsrc + (size_t)(jj * 64) * 256, Bs + jj * 4096 + wv * 512);
        __syncthreads();
#pragma unroll
        for (int kk = 0; kk < 2; ++kk) {
          bf16x8_t bfr[2];
#pragma unroll
          for (int ni = 0; ni < 2; ++ni) {
            const int nl = wn + ni * 16 + ln15;
            bfr[ni] = *(const bf16x8_t*)(Bs + (nl * 8 + ((kk * 4 + kgrp) ^ (nl & 7))) * 8);
          }
#pragma unroll
          for (int mi = 0; mi < 2; ++mi) {
            const int row = mi * 16 + ln15;
            const int ck = (k0 >> 3) + kk * 4 + kgrp;
            bf16x8_t af = *(const bf16x8_t*)(An + row * 256 + ((ck ^ (row & 7)) << 3));
#pragma unroll
            for (int ni = 0; ni < 2; ++ni)
              a2[mi][ni] = __builtin_amdgcn_mfma_f32_16x16x32_bf16(af, bfr[ni], a2[mi][ni], 0, 0, 0);
          }
        }
        __syncthreads();
      }
#pragma unroll
      for (int mi = 0; mi < 2; ++mi) {
#pragma unroll
        for (int ni = 0; ni < 2; ++ni) {
          const int ocol = n0 + wn + ni * 16 + ln15;
          const float b2 = bn[ocol];
          const int orow0 = bm + mi * 16 + kgrp * 4;
#pragma unroll
          for (int r = 0; r < 4; ++r) {
            float o = a2[mi][ni][r] + b2;
            if (NACT == 1) o = gelu_f(o);
            outn[(size_t)(orow0 + r) * NEXT_N + ocol] = (__bf16)o;
          }
        }
      }
    }
  }
}

// ---------- MFMA flash attention, 8 waves / 128 q-rows per block ------------
template<bool CAUSAL>
__global__ __launch_bounds__(512)
void attn_mfma(const __bf16* __restrict__ Q, const __bf16* __restrict__ K,
               const __bf16* __restrict__ V, __bf16* __restrict__ O,
               int KVROWS, int qs, int ks) {
  const int b = blockIdx.x >> 3, h = blockIdx.x & 7;
  const int qt = blockIdx.y;
  const int tid = threadIdx.x, lane = tid & 63, wv = tid >> 6;   // wv 0..7
  const int ln15 = lane & 15, kgrp = lane >> 4, kgrp8 = kgrp * 8;

  __shared__ __bf16 K_lds[64][36];
  __shared__ __bf16 Vt_lds[32][72];
  __shared__ __bf16 P_lds[8][16][72];

  const int q_glob = qt * 128 + wv * 16 + ln15;
  const bf16x8_t qfrag = *(const bf16x8_t*)(Q + (size_t)(b * T_ + q_glob) * qs + h * HD_ + kgrp8);

  const int s_r = tid >> 3, s_c4 = (tid & 7) * 4;
  const __bf16* Kb = K + (size_t)(b * KVROWS + s_r) * ks + h * HD_ + s_c4;
  const __bf16* Vb = V + (size_t)(b * KVROWS + s_r) * ks + h * HD_ + s_c4;

  f32x4_t o0 = (f32x4_t){0.f,0.f,0.f,0.f}, o1 = (f32x4_t){0.f,0.f,0.f,0.f};
  float m = -3.0e38f, l = 0.f;
  const float SCALE = 0.17677669529663689f;
  const int slim = CAUSAL ? (qt + 1) * 128 : KVROWS;

  for (int s0 = 0; s0 < slim; s0 += 64) {
    *(uint2*)&K_lds[s_r][s_c4] = *(const uint2*)(Kb + (size_t)s0 * ks);
    bf16x4_t vv = *(const bf16x4_t*)(Vb + (size_t)s0 * ks);
#pragma unroll
    for (int jj = 0; jj < 4; ++jj) Vt_lds[s_c4 + jj][s_r] = vv[jj];
    __syncthreads();

    f32x4_t sa[4];
#pragma unroll
    for (int c = 0; c < 4; ++c) {
      bf16x8_t kf = *(const bf16x8_t*)&K_lds[c * 16 + ln15][kgrp8];
      sa[c] = __builtin_amdgcn_mfma_f32_16x16x32_bf16(kf, qfrag, (f32x4_t){0.f,0.f,0.f,0.f}, 0, 0, 0);
    }
    float v[16];
#pragma unroll
    for (int c = 0; c < 4; ++c)
#pragma unroll
      for (int r = 0; r < 4; ++r) {
        float s = sa[c][r] * SCALE;
        if (CAUSAL && (s0 + c * 16 + kgrp * 4 + r) > q_glob) s += -1e9f;
        v[c * 4 + r] = s;
      }
    float tmax = v[0];
#pragma unroll
    for (int r = 1; r < 16; ++r) tmax = fmaxf(tmax, v[r]);
    tmax = fmaxf(tmax, __shfl_xor(tmax, 16));
    tmax = fmaxf(tmax, __shfl_xor(tmax, 32));
    float mnew = fmaxf(m, tmax);
    float corr = __expf(m - mnew);

    float lsum = 0.f;
#pragma unroll
    for (int c = 0; c < 4; ++c) {
      bf16x4_t pc;
#pragma unroll
      for (int r = 0; r < 4; ++r) {
        float e = __expf(v[c * 4 + r] - mnew);
        lsum += e;
        pc[r] = (__bf16)e;
      }
      *(bf16x4_t*)&P_lds[wv][ln15][c * 16 + kgrp * 4] = pc;
    }
    lsum += __shfl_xor(lsum, 16);
    lsum += __shfl_xor(lsum, 32);
    l = l * corr + lsum;
    m = mnew;

    const float c0 = __shfl(corr, kgrp * 4 + 0);
    const float c1 = __shfl(corr, kgrp * 4 + 1);
    const float c2 = __shfl(corr, kgrp * 4 + 2);
    const float c3 = __shfl(corr, kgrp * 4 + 3);
    o0[0] *= c0; o0[1] *= c1; o0[2] *= c2; o0[3] *= c3;
    o1[0] *= c0; o1[1] *= c1; o1[2] *= c2; o1[3] *= c3;

    bf16x8_t pLo = *(const bf16x8_t*)&P_lds[wv][ln15][kgrp8];
    bf16x8_t pHi = *(const bf16x8_t*)&P_lds[wv][ln15][32 + kgrp8];
    bf16x8_t v0l = *(const bf16x8_t*)&Vt_lds[ln15][kgrp8];
    bf16x8_t v0h = *(const bf16x8_t*)&Vt_lds[ln15][32 + kgrp8];
    bf16x8_t v1l = *(const bf16x8_t*)&Vt_lds[16 + ln15][kgrp8];
    bf16x8_t v1h = *(const bf16x8_t*)&Vt_lds[16 + ln15][32 + kgrp8];
    o0 = __builtin_amdgcn_mfma_f32_16x16x32_bf16(pLo, v0l, o0, 0, 0, 0);
    o0 = __builtin_amdgcn_mfma_f32_16x16x32_bf16(pHi, v0h, o0, 0, 0, 0);
    o1 = __builtin_amdgcn_mfma_f32_16x16x32_bf16(pLo, v1l, o1, 0, 0, 0);
    o1 = __builtin_amdgcn_mfma_f32_16x16x32_bf16(pHi, v1h, o1, 0, 0, 0);
    __syncthreads();
  }

  const float inv = 1.f / l;
  const float i0 = __shfl(inv, kgrp * 4 + 0);
  const float i1 = __shfl(inv, kgrp * 4 + 1);
  const float i2 = __shfl(inv, kgrp * 4 + 2);
  const float i3 = __shfl(inv, kgrp * 4 + 3);
  __bf16* Op = O + (size_t)(b * T_ + qt * 128 + wv * 16 + kgrp * 4) * D_ + h * HD_;
  Op[0 * D_ + ln15] = (__bf16)(o0[0] * i0);  Op[0 * D_ + 16 + ln15] = (__bf16)(o1[0] * i0);
  Op[1 * D_ + ln15] = (__bf16)(o0[1] * i1);  Op[1 * D_ + 16 + ln15] = (__bf16)(o1[1] * i1);
  Op[2 * D_ + ln15] = (__bf16)(o0[2] * i2);  Op[2 * D_ + 16 + ln15] = (__bf16)(o1[2] * i2);
  Op[3 * D_ + ln15] = (__bf16)(o0[3] * i3);  Op[3 * D_ + 16 + ln15] = (__bf16)(o1[3] * i3);
}

// ---------------- final matvec: out = h(BTx128) @ Wp2(128x1) + bp2 -----------
__global__ __launch_bounds__(256)
void head2_kernel(const float* __restrict__ hb, const float* __restrict__ w,
                  const float* __restrict__ bias, float* __restrict__ out) {
  const int row = blockIdx.x * 4 + (threadIdx.x >> 6);
  const int lane = threadIdx.x & 63;
  float a = hb[(size_t)row * 128 + lane] * w[lane]
          + hb[(size_t)row * 128 + 64 + lane] * w[64 + lane];
#pragma unroll
  for (int off = 32; off; off >>= 1) a += __shfl_xor(a, off);
  if (lane == 0) out[row] = a + bias[0];
}

extern "C" void kernel_launch(void* const* d_in, const int* in_sizes, int n_in,
                              void* d_out, int out_size, void* d_ws, size_t ws_size,
                              hipStream_t stream) {
  const float* tgt    = (const float*)d_in[0];
  const float* memory = (const float*)d_in[1];
  const float* W_emb  = (const float*)d_in[2];
  const float* b_emb  = (const float*)d_in[3];
  const float* W_enc  = (const float*)d_in[4];
  const float* b_enc  = (const float*)d_in[5];
  const float* Wq_s = (const float*)d_in[6];  const float* bq_s = (const float*)d_in[7];
  const float* Wk_s = (const float*)d_in[8];  const float* bk_s = (const float*)d_in[9];
  const float* Wv_s = (const float*)d_in[10]; const float* bv_s = (const float*)d_in[11];
  const float* Wo_s = (const float*)d_in[12]; const float* bo_s = (const float*)d_in[13];
  const float* Wq_c = (const float*)d_in[14]; const float* bq_c = (const float*)d_in[15];
  const float* Wk_c = (const float*)d_in[16]; const float* bk_c = (const float*)d_in[17];
  const float* Wv_c = (const float*)d_in[18]; const float* bv_c = (const float*)d_in[19];
  const float* Wo_c = (const float*)d_in[20]; const float* bo_c = (const float*)d_in[21];
  const float* g1  = (const float*)d_in[22]; const float* be1 = (const float*)d_in[23];
  const float* g2  = (const float*)d_in[24]; const float* be2 = (const float*)d_in[25];
  const float* g3  = (const float*)d_in[26]; const float* be3 = (const float*)d_in[27];
  const float* Wf1 = (const float*)d_in[28]; const float* bf1 = (const float*)d_in[29];
  const float* Wf2 = (const float*)d_in[30]; const float* bf2 = (const float*)d_in[31];
  const float* Wp1 = (const float*)d_in[32]; const float* bp1 = (const float*)d_in[33];
  const float* Wp2 = (const float*)d_in[34]; const float* bp2 = (const float*)d_in[35];

  // ---- workspace layout (float units), ~141 MB, disjoint hot buffers ----
  float*  x     = (float*)d_ws;                             // 4,194,304 f
  __bf16* xbf   = (__bf16*)(x + (size_t)4194304);           // 2,097,152 f
  __bf16* membf = xbf + (size_t)4194304;                    // 1,048,576 f
  __bf16* wt    = (__bf16*)((float*)membf + 1048576);       // 2,211,840 f
  float*  bcat  = (float*)(wt + 4423680);                   // 8,192 f
  __bf16* kvall = (__bf16*)(bcat + 8192);                   // 8,388,608 f (8192x2048)
  __bf16* qkv   = kvall + (size_t)16777216;                 // 6,291,456 f (16384x768)
  __bf16* ff    = qkv + (size_t)12582912;                   // 8,388,608 f (16384x1024)
  __bf16* qc    = ff + (size_t)16777216;                    // 2,097,152 f (16384x256)
  __bf16* ao    = qc + (size_t)4194304;                     // 2,097,152 f (16384x256)
  // aliases (phase-disjoint):
  __bf16* memb = ff;                                        // BS*ED bf16 (pre-layer only)
  float*  hbuf = (float*)qc;                                // BT*128 f32 (head phase)

  const size_t o_enc  = 0;
  const size_t o_qkv  = 196608;
  const size_t o_qcw  = 983040;
  const size_t o_kvw  = 1245184;
  const size_t o_os   = 1769472;
  const size_t o_oc   = 2031616;
  const size_t o_f1   = 2293760;
  const size_t o_f2   = 3342336;
  const size_t o_p1   = 4390912;

  TDs td;
  td.d[0]  = {W_enc, o_enc,           ED_, D_,  1, 0};
  td.d[1]  = {Wq_s,  o_qkv + 0,       D_,  D_,  L_, 196608};
  td.d[2]  = {Wk_s,  o_qkv + 65536,   D_,  D_,  L_, 196608};
  td.d[3]  = {Wv_s,  o_qkv + 131072,  D_,  D_,  L_, 196608};
  td.d[4]  = {Wq_c,  o_qcw,           D_,  D_,  L_, 65536};
  td.d[5]  = {Wk_c,  o_kvw + 0,       D_,  D_,  L_, 131072};
  td.d[6]  = {Wv_c,  o_kvw + 65536,   D_,  D_,  L_, 131072};
  td.d[7]  = {Wo_s,  o_os,            D_,  D_,  L_, 65536};
  td.d[8]  = {Wo_c,  o_oc,            D_,  D_,  L_, 65536};
  td.d[9]  = {Wf1,   o_f1,            D_,  FF_, L_, 262144};
  td.d[10] = {Wf2,   o_f2,            FF_, D_,  L_, 262144};
  td.d[11] = {Wp1,   o_p1,            D_,  128, 1, 0};

  dim3 blk(256);
  cvt_bf16_kernel<<<BS_ * ED_ / 1024, blk, 0, stream>>>(memory, memb);
  transpose_cvt_kernel<<<dim3(1024, 12), blk, 0, stream>>>(td, wt);
  bias_concat_kernel<<<20, blk, 0, stream>>>(bq_s, bk_s, bv_s, bk_c, bv_c, bcat);
  embed_kernel<<<BT_ * D_ / 256, blk, 0, stream>>>(tgt, W_emb, b_emb, x, xbf);

  const float* bqkv = bcat;            // [L][768]
  const float* bkv  = bcat + 3072;     // [L*512] linear
  const dim3 gA(B_ * H_, T_ / 128);

  // encoder proj: memb(8192x768) -> membf(8192x256)
  gemm_bf<0,1><<<64 * 4, blk, 0, stream>>>(memb, wt + o_enc, b_enc, membf, D_, ED_, 4, 8);
  // ALL layers' cross-KV: membf @ [2048x256]^T -> kvall(8192x2048)
  gemm_bf2<0,1><<<64 * 16, blk, 0, stream>>>(membf, wt + o_kvw, bkv, kvall, 2048, D_, 16, 8);
  // layer-0 QKV
  gemm_bf2<0,1><<<128 * 6, blk, 0, stream>>>(xbf, wt + o_qkv, bqkv, qkv, 768, D_, 6, 16);

  for (int i = 0; i < L_; ++i) {
    // ---- self attention + [O-proj + LN1 + cross-Q] ----
    attn_mfma<true><<<gA, dim3(512), 0, stream>>>(qkv, qkv + 256, qkv + 512, ao, T_, 768, 768);
    gemm_ln_next<256,0,0><<<512, dim3(512), 0, stream>>>(
        ao, wt + o_os + (size_t)i * 65536, bo_s + i * D_, g1 + i * D_, be1 + i * D_,
        x, xbf, D_, 64, wt + o_qcw + (size_t)i * 65536, bq_c + i * D_, qc);
    // ---- cross attention + [O-proj + LN2 + FF1(gelu)] ----
    attn_mfma<false><<<gA, dim3(512), 0, stream>>>(qc, kvall + i * 512, kvall + i * 512 + 256, ao, S_, 256, 2048);
    gemm_ln_next<1024,1,0><<<512, dim3(512), 0, stream>>>(
        ao, wt + o_oc + (size_t)i * 65536, bo_c + i * D_, g2 + i * D_, be2 + i * D_,
        x, xbf, D_, 64, wt + o_f1 + (size_t)i * 262144, bf1 + i * FF_, ff);
    // ---- FF2 + LN3 + [next-layer QKV] ----
    if (i < L_ - 1) {
      gemm_ln_next<768,0,0><<<512, dim3(512), 0, stream>>>(
          ff, wt + o_f2 + (size_t)i * 262144, bf2 + i * D_, g3 + i * D_, be3 + i * D_,
          x, xbf, FF_, 64, wt + o_qkv + (size_t)(i + 1) * 196608, bqkv + (i + 1) * 768, qkv);
    } else {
      gemm_ln_next<0,0,1><<<512, dim3(512), 0, stream>>>(
          ff, wt + o_f2 + (size_t)i * 262144, bf2 + i * D_, g3 + i * D_, be3 + i * D_,
          x, xbf, FF_, 64, (const __bf16*)nullptr, (const float*)nullptr, (__bf16*)nullptr);
    }
  }
  // ---- head ----
  gemm_bf<1,0><<<128 * 2, blk, 0, stream>>>(xbf, wt + o_p1, bp1, hbuf, 128, D_, 2, 16);
  head2_kernel<<<BT_ / 4, blk, 0, stream>>>(hbuf, Wp2, bp2, (float*)d_out);
}

// Round 15
// 646.064 us; speedup vs baseline: 1.0198x; 1.0198x over previous
//
#include <hip/hip_runtime.h>
#include <math.h>

#define B_  32
#define T_  512
#define S_  256
#define D_  256
#define H_  8
#define HD_ 32
#define FF_ 1024
#define ED_ 768
#define L_  4
#define BT_ (B_*T_)   // 16384
#define BS_ (B_*S_)   // 8192

typedef __bf16 bf16x8_t __attribute__((ext_vector_type(8)));
typedef __bf16 bf16x4_t __attribute__((ext_vector_type(4)));
typedef float  f32x4_t  __attribute__((ext_vector_type(4)));

__device__ __forceinline__ float gelu_f(float v) {
  return 0.5f * v * (1.f + erff(v * 0.7071067811865476f));
}

// async global->LDS, 16B per lane; LDS dest = wave-uniform base + lane*16
__device__ __forceinline__ void gl16(const __bf16* gsrc, __bf16* ldst) {
  __builtin_amdgcn_global_load_lds(
      (const __attribute__((address_space(1))) unsigned int*)gsrc,
      (__attribute__((address_space(3))) unsigned int*)ldst, 16, 0, 0);
}

// ---------------- embed: x = tgt*W_emb + b_emb + pos_encoding ----------------
__global__ __launch_bounds__(256)
void embed_kernel(const float* __restrict__ tgt, const float* __restrict__ Wemb,
                  const float* __restrict__ bemb, float* __restrict__ x,
                  __bf16* __restrict__ xbf) {
  int i = blockIdx.x * 256 + threadIdx.x;
  int d  = i & (D_ - 1);
  int bt = i >> 8;
  int t  = bt & (T_ - 1);
  int p  = d >> 1;
  float div = expf((float)(2 * p) * (-9.210340371976184f / (float)D_));
  float arg = (float)t * div;
  float pe = (d & 1) ? cosf(arg) : sinf(arg);
  float v = tgt[bt] * Wemb[d] + bemb[d] + pe;
  x[i] = v;
  xbf[i] = (__bf16)v;
}

// ---------------- fp32 -> bf16 bulk convert ----------------------------------
__global__ __launch_bounds__(256)
void cvt_bf16_kernel(const float* __restrict__ in, __bf16* __restrict__ out) {
  int i = (blockIdx.x * 256 + threadIdx.x) * 4;
  float4 v = *(const float4*)(in + i);
  bf16x4_t o;
  o[0] = (__bf16)v.x; o[1] = (__bf16)v.y; o[2] = (__bf16)v.z; o[3] = (__bf16)v.w;
  *(bf16x4_t*)(out + i) = o;
}

// ------------- weight pre-pass: transpose [K][N] fp32 -> [N][K] bf16 ---------
struct TD { const float* src; size_t dst; int K, N, nb; size_t lstride; };
struct TDs { TD d[12]; };

__global__ __launch_bounds__(256)
void transpose_cvt_kernel(TDs a, __bf16* __restrict__ wt) {
  __shared__ float tile[32][33];
  TD t = a.d[blockIdx.y];
  const int kt = t.K >> 5, nt = t.N >> 5;
  const int per = kt * nt, tot = per * t.nb;
  const int id = blockIdx.x;
  if (id >= tot) return;
  const int b = id / per;
  const int r2 = id - b * per;
  const int kti = r2 / nt;
  const int nti = r2 - kti * nt;
  const int c = threadIdx.x & 31, r0 = threadIdx.x >> 5;
  const float* src = t.src + (size_t)b * t.K * t.N;
  __bf16* dst = wt + t.dst + (size_t)b * t.lstride;
#pragma unroll
  for (int j = 0; j < 4; ++j) {
    int rr = r0 + j * 8;
    tile[rr][c] = src[(size_t)(kti * 32 + rr) * t.N + nti * 32 + c];
  }
  __syncthreads();
#pragma unroll
  for (int j = 0; j < 4; ++j) {
    int rr = r0 + j * 8;
    dst[(size_t)(nti * 32 + rr) * t.K + kti * 32 + c] = (__bf16)tile[c][rr];
  }
}

// ---------------- concat biases: [L][768] self-qkv, then [L][512] cross-kv ---
__global__ __launch_bounds__(256)
void bias_concat_kernel(const float* __restrict__ bq_s, const float* __restrict__ bk_s,
                        const float* __restrict__ bv_s, const float* __restrict__ bk_c,
                        const float* __restrict__ bv_c, float* __restrict__ dst) {
  int idx = blockIdx.x * 256 + threadIdx.x;
  if (idx >= 5120) return;
  if (idx < 3072) {
    int l = idx / 768, c = idx - l * 768;
    float v = (c < 256) ? bq_s[l * 256 + c]
            : (c < 512) ? bk_s[l * 256 + c - 256]
                        : bv_s[l * 256 + c - 512];
    dst[idx] = v;
  } else {
    int j = idx - 3072;
    int l = j / 512, c = j - l * 512;
    float v = (c < 256) ? bk_c[l * 256 + c] : bv_c[l * 256 + c - 256];
    dst[idx] = v;
  }
}

// ------------- bf16 MFMA GEMM, tile 128x64 ----------------------------------
template<int ACT, int OBF>
__global__ __launch_bounds__(256, 3)
void gemm_bf(const __bf16* __restrict__ A, const __bf16* __restrict__ Bt,
             const float* __restrict__ bias, void* __restrict__ Cv,
             int N, int K, int nN, int ppx) {
  __shared__ __bf16 As[128 * 64];
  __shared__ __bf16 Bs[64 * 64];
  const int tid = threadIdx.x, lane = tid & 63, wv = tid >> 6;
  const int wm = (wv & 1) * 64, wn = (wv >> 1) * 32;
  const int ln15 = lane & 15, kgrp = lane >> 4;
  const int xcd = blockIdx.x & 7, j = blockIdx.x >> 3;
  const int bm = (xcd * ppx + j / nN) * 128;
  const int bn = (j % nN) * 64;

  const int r8 = lane >> 3;
  const int scol = (lane & 7) ^ r8;
  const __bf16* a_g = A  + (size_t)(bm + wv * 32 + r8) * K + scol * 8;
  const __bf16* b_g = Bt + (size_t)(bn + wv * 16 + r8) * K + scol * 8;
  __bf16* a_l = As + wv * 2048;
  __bf16* b_l = Bs + wv * 1024;

  const int xk0 = kgrp ^ (ln15 & 7);
  const int xk1 = (4 + kgrp) ^ (ln15 & 7);

  f32x4_t acc[4][2];
#pragma unroll
  for (int mi = 0; mi < 4; ++mi)
#pragma unroll
    for (int ni = 0; ni < 2; ++ni) acc[mi][ni] = (f32x4_t){0.f, 0.f, 0.f, 0.f};

  for (int k0 = 0; k0 < K; k0 += 64) {
    gl16(a_g + k0,                a_l);
    gl16(a_g + k0 + (size_t)8*K,  a_l + 512);
    gl16(a_g + k0 + (size_t)16*K, a_l + 1024);
    gl16(a_g + k0 + (size_t)24*K, a_l + 1536);
    gl16(b_g + k0,                b_l);
    gl16(b_g + k0 + (size_t)8*K,  b_l + 512);
    __syncthreads();

#pragma unroll
    for (int kk = 0; kk < 2; ++kk) {
      const int xk = kk ? xk1 : xk0;
      bf16x8_t b0 = *(const bf16x8_t*)(Bs + ((wn + ln15) * 8 + xk) * 8);
      bf16x8_t b1 = *(const bf16x8_t*)(Bs + ((wn + 16 + ln15) * 8 + xk) * 8);
#pragma unroll
      for (int mi = 0; mi < 4; ++mi) {
        bf16x8_t af = *(const bf16x8_t*)(As + ((wm + mi * 16 + ln15) * 8 + xk) * 8);
        acc[mi][0] = __builtin_amdgcn_mfma_f32_16x16x32_bf16(af, b0, acc[mi][0], 0, 0, 0);
        acc[mi][1] = __builtin_amdgcn_mfma_f32_16x16x32_bf16(af, b1, acc[mi][1], 0, 0, 0);
      }
    }
    __syncthreads();
  }

#pragma unroll
  for (int mi = 0; mi < 4; ++mi) {
#pragma unroll
    for (int ni = 0; ni < 2; ++ni) {
      const int ocol = bn + wn + ni * 16 + ln15;
      const float bv = bias[ocol];
      const int orow0 = bm + wm + mi * 16 + kgrp * 4;
#pragma unroll
      for (int r = 0; r < 4; ++r) {
        float o = acc[mi][ni][r] + bv;
        if (ACT == 1) o = gelu_f(o);
        if (OBF) ((__bf16*)Cv)[(size_t)(orow0 + r) * N + ocol] = (__bf16)o;
        else     ((float*)Cv)[(size_t)(orow0 + r) * N + ocol] = o;
      }
    }
  }
}

// ------------- bf16 MFMA GEMM, tile 128x128 (wide-N: QKV0, KVall, FF1) -------
template<int ACT, int OBF>
__global__ __launch_bounds__(256, 3)
void gemm_bf2(const __bf16* __restrict__ A, const __bf16* __restrict__ Bt,
              const float* __restrict__ bias, void* __restrict__ Cv,
              int N, int K, int nN, int ppx) {
  __shared__ __bf16 As[128 * 64];
  __shared__ __bf16 Bs[128 * 64];
  const int tid = threadIdx.x, lane = tid & 63, wv = tid >> 6;
  const int wm = (wv & 1) * 64, wn = (wv >> 1) * 64;
  const int ln15 = lane & 15, kgrp = lane >> 4;
  const int xcd = blockIdx.x & 7, j = blockIdx.x >> 3;
  const int bm = (xcd * ppx + j / nN) * 128;
  const int bn = (j % nN) * 128;

  const int r8 = lane >> 3;
  const int scol = (lane & 7) ^ r8;
  const __bf16* a_g = A  + (size_t)(bm + wv * 32 + r8) * K + scol * 8;
  const __bf16* b_g = Bt + (size_t)(bn + wv * 32 + r8) * K + scol * 8;
  __bf16* a_l = As + wv * 2048;
  __bf16* b_l = Bs + wv * 2048;

  const int xk0 = kgrp ^ (ln15 & 7);
  const int xk1 = (4 + kgrp) ^ (ln15 & 7);

  f32x4_t acc[4][4];
#pragma unroll
  for (int mi = 0; mi < 4; ++mi)
#pragma unroll
    for (int ni = 0; ni < 4; ++ni) acc[mi][ni] = (f32x4_t){0.f, 0.f, 0.f, 0.f};

  for (int k0 = 0; k0 < K; k0 += 64) {
    gl16(a_g + k0,                a_l);
    gl16(a_g + k0 + (size_t)8*K,  a_l + 512);
    gl16(a_g + k0 + (size_t)16*K, a_l + 1024);
    gl16(a_g + k0 + (size_t)24*K, a_l + 1536);
    gl16(b_g + k0,                b_l);
    gl16(b_g + k0 + (size_t)8*K,  b_l + 512);
    gl16(b_g + k0 + (size_t)16*K, b_l + 1024);
    gl16(b_g + k0 + (size_t)24*K, b_l + 1536);
    __syncthreads();

#pragma unroll
    for (int kk = 0; kk < 2; ++kk) {
      const int xk = kk ? xk1 : xk0;
      bf16x8_t bfr[4];
#pragma unroll
      for (int ni = 0; ni < 4; ++ni)
        bfr[ni] = *(const bf16x8_t*)(Bs + ((wn + ni * 16 + ln15) * 8 + xk) * 8);
#pragma unroll
      for (int mi = 0; mi < 4; ++mi) {
        bf16x8_t af = *(const bf16x8_t*)(As + ((wm + mi * 16 + ln15) * 8 + xk) * 8);
#pragma unroll
        for (int ni = 0; ni < 4; ++ni)
          acc[mi][ni] = __builtin_amdgcn_mfma_f32_16x16x32_bf16(af, bfr[ni], acc[mi][ni], 0, 0, 0);
      }
    }
    __syncthreads();
  }

#pragma unroll
  for (int mi = 0; mi < 4; ++mi) {
#pragma unroll
    for (int ni = 0; ni < 4; ++ni) {
      const int ocol = bn + wn + ni * 16 + ln15;
      const float bv = bias[ocol];
      const int orow0 = bm + wm + mi * 16 + kgrp * 4;
#pragma unroll
      for (int r = 0; r < 4; ++r) {
        float o = acc[mi][ni][r] + bv;
        if (ACT == 1) o = gelu_f(o);
        if (OBF) ((__bf16*)Cv)[(size_t)(orow0 + r) * N + ocol] = (__bf16)o;
        else     ((float*)Cv)[(size_t)(orow0 + r) * N + ocol] = o;
      }
    }
  }
}

// ------ fused GEMM(32x256) + residual + LN [+ next GEMM from LDS xnorm] -----
// R15 = R13's proven 4-wave kernel. FF1 unfused (phase2 only for qc / QKV).
template<int NEXT_N, int NACT, int WXBF>
__global__ __launch_bounds__(256, 2)
void gemm_ln_next(const __bf16* __restrict__ A, const __bf16* __restrict__ Bt,
                  const float* __restrict__ bias, const float* __restrict__ g,
                  const float* __restrict__ bta, float* __restrict__ x,
                  __bf16* __restrict__ xbf, int K, int ppx,
                  const __bf16* __restrict__ Wn, const float* __restrict__ bn,
                  __bf16* __restrict__ outn) {
  __shared__ __bf16 As[32 * 64];      // 4 KB
  __shared__ __bf16 Bs[256 * 64];     // 32 KB (phase-1 B / phase-2 W)
  __shared__ __bf16 An[32 * 256];     // 16 KB normalized rows (phase-2 A)
  __shared__ float red[32][8];        // 1 KB
  const int tid = threadIdx.x, lane = tid & 63, wv = tid >> 6;
  const int wn = wv * 64;                       // 1M x 4N
  const int ln15 = lane & 15, kgrp = lane >> 4;
  const int xcd = blockIdx.x & 7, j = blockIdx.x >> 3;
  const int bm = (xcd * ppx + j) * 32;

  const int sr = tid >> 3;                      // 0..31
  const int sch = (tid & 7) ^ (sr & 7);         // pre-swizzled source chunk
  const __bf16* a_g = A  + (size_t)(bm + sr) * K + sch * 8;
  const __bf16* b_g = Bt + (size_t)sr * K + sch * 8;

  f32x4_t acc[2][4];
#pragma unroll
  for (int mi = 0; mi < 2; ++mi)
#pragma unroll
    for (int ni = 0; ni < 4; ++ni) acc[mi][ni] = (f32x4_t){0.f, 0.f, 0.f, 0.f};

  // ---- phase 1: y(32x256) = A @ Bt^T ----
  for (int k0 = 0; k0 < K; k0 += 64) {
    gl16(a_g + k0, As + wv * 512);
#pragma unroll
    for (int jj = 0; jj < 8; ++jj)
      gl16(b_g + k0 + (size_t)(jj * 32) * K, Bs + jj * 2048 + wv * 512);
    __syncthreads();
#pragma unroll
    for (int kk = 0; kk < 2; ++kk) {
      bf16x8_t bfr[4];
#pragma unroll
      for (int ni = 0; ni < 4; ++ni) {
        const int nl = wn + ni * 16 + ln15;
        bfr[ni] = *(const bf16x8_t*)(Bs + (nl * 8 + ((kk * 4 + kgrp) ^ (nl & 7))) * 8);
      }
#pragma unroll
      for (int mi = 0; mi < 2; ++mi) {
        const int rl = mi * 16 + ln15;
        bf16x8_t af = *(const bf16x8_t*)(As + (rl * 8 + ((kk * 4 + kgrp) ^ (rl & 7))) * 8);
#pragma unroll
        for (int ni = 0; ni < 4; ++ni)
          acc[mi][ni] = __builtin_amdgcn_mfma_f32_16x16x32_bf16(af, bfr[ni], acc[mi][ni], 0, 0, 0);
      }
    }
    __syncthreads();
  }

  // ---- phase-1 epilogue: residual + LN over 256 cols ----
  const int c0 = wn + ln15;
  float bs[4], gg[4], bb[4];
#pragma unroll
  for (int ni = 0; ni < 4; ++ni) {
    bs[ni] = bias[c0 + ni * 16];
    gg[ni] = g[c0 + ni * 16];
    bb[ni] = bta[c0 + ni * 16];
  }
  float v[2][4][4];
#pragma unroll
  for (int mi = 0; mi < 2; ++mi) {
#pragma unroll
    for (int r = 0; r < 4; ++r) {
      const int rl = mi * 16 + kgrp * 4 + r;
      const int row = bm + rl;
      float s = 0.f, q = 0.f;
#pragma unroll
      for (int ni = 0; ni < 4; ++ni) {
        float t = acc[mi][ni][r] + bs[ni] + x[(size_t)row * 256 + c0 + ni * 16];
        v[mi][ni][r] = t; s += t; q += t * t;
      }
      s += __shfl_xor(s, 1); s += __shfl_xor(s, 2);
      s += __shfl_xor(s, 4); s += __shfl_xor(s, 8);
      q += __shfl_xor(q, 1); q += __shfl_xor(q, 2);
      q += __shfl_xor(q, 4); q += __shfl_xor(q, 8);
      if (ln15 == 0) {
        red[rl][wv * 2 + 0] = s;
        red[rl][wv * 2 + 1] = q;
      }
    }
  }
  __syncthreads();
#pragma unroll
  for (int mi = 0; mi < 2; ++mi) {
#pragma unroll
    for (int r = 0; r < 4; ++r) {
      const int rl = mi * 16 + kgrp * 4 + r;
      const int row = bm + rl;
      const float ms = red[rl][0] + red[rl][2] + red[rl][4] + red[rl][6];
      const float mq = red[rl][1] + red[rl][3] + red[rl][5] + red[rl][7];
      const float mean = ms * (1.f / 256.f);
      const float var  = mq * (1.f / 256.f) - mean * mean;
      const float rstd = rsqrtf(fmaxf(var, 0.f) + 1e-5f);
#pragma unroll
      for (int ni = 0; ni < 4; ++ni) {
        const int c = c0 + ni * 16;
        float o = (v[mi][ni][r] - mean) * rstd * gg[ni] + bb[ni];
        x[(size_t)row * 256 + c] = o;
        __bf16 ob = (__bf16)o;
        if (WXBF) xbf[(size_t)row * 256 + c] = ob;
        if (NEXT_N > 0)
          An[rl * 256 + (((c >> 3) ^ (rl & 7)) << 3) + (c & 7)] = ob;
      }
    }
  }

  // ---- phase 2: outn = xnorm @ Wn^T + bn ----
  if (NEXT_N > 0) {
    for (int pass = 0; pass < NEXT_N / 256; ++pass) {
      const int n0 = pass * 256;
      f32x4_t a2[2][4];
#pragma unroll
      for (int mi = 0; mi < 2; ++mi)
#pragma unroll
        for (int ni = 0; ni < 4; ++ni) a2[mi][ni] = (f32x4_t){0.f, 0.f, 0.f, 0.f};

      for (int k0 = 0; k0 < 256; k0 += 64) {
        const __bf16* wsrc = Wn + (size_t)(n0 + sr) * 256 + k0 + sch * 8;
#pragma unroll
        for (int jj = 0; jj < 8; ++jj)
          gl16(wsrc + (size_t)(jj * 32) * 256, Bs + jj * 2048 + wv * 512);
        __syncthreads();
#pragma unroll
        for (int kk = 0; kk < 2; ++kk) {
          bf16x8_t bfr[4];
#pragma unroll
          for (int ni = 0; ni < 4; ++ni) {
            const int nl = wn + ni * 16 + ln15;
            bfr[ni] = *(const bf16x8_t*)(Bs + (nl * 8 + ((kk * 4 + kgrp) ^ (nl & 7))) * 8);
          }
#pragma unroll
          for (int mi = 0; mi < 2; ++mi) {
            const int row = mi * 16 + ln15;
            const int ck = (k0 >> 3) + kk * 4 + kgrp;
            bf16x8_t af = *(const bf16x8_t*)(An + row * 256 + ((ck ^ (row & 7)) << 3));
#pragma unroll
            for (int ni = 0; ni < 4; ++ni)
              a2[mi][ni] = __builtin_amdgcn_mfma_f32_16x16x32_bf16(af, bfr[ni], a2[mi][ni], 0, 0, 0);
          }
        }
        __syncthreads();
      }
#pragma unroll
      for (int mi = 0; mi < 2; ++mi) {
#pragma unroll
        for (int ni = 0; ni < 4; ++ni) {
          const int ocol = n0 + wn + ni * 16 + ln15;
          const float b2 = bn[ocol];
          const int orow0 = bm + mi * 16 + kgrp * 4;
#pragma unroll
          for (int r = 0; r < 4; ++r) {
            float o = a2[mi][ni][r] + b2;
            if (NACT == 1) o = gelu_f(o);
            outn[(size_t)(orow0 + r) * NEXT_N + ocol] = (__bf16)o;
          }
        }
      }
    }
  }
}

// ---------- MFMA flash attention, 8 waves / 128 q-rows per block ------------
template<bool CAUSAL>
__global__ __launch_bounds__(512)
void attn_mfma(const __bf16* __restrict__ Q, const __bf16* __restrict__ K,
               const __bf16* __restrict__ V, __bf16* __restrict__ O,
               int KVROWS, int qs, int ks) {
  const int b = blockIdx.x >> 3, h = blockIdx.x & 7;
  const int qt = blockIdx.y;
  const int tid = threadIdx.x, lane = tid & 63, wv = tid >> 6;   // wv 0..7
  const int ln15 = lane & 15, kgrp = lane >> 4, kgrp8 = kgrp * 8;

  __shared__ __bf16 K_lds[64][36];
  __shared__ __bf16 Vt_lds[32][72];
  __shared__ __bf16 P_lds[8][16][72];

  const int q_glob = qt * 128 + wv * 16 + ln15;
  const bf16x8_t qfrag = *(const bf16x8_t*)(Q + (size_t)(b * T_ + q_glob) * qs + h * HD_ + kgrp8);

  const int s_r = tid >> 3, s_c4 = (tid & 7) * 4;
  const __bf16* Kb = K + (size_t)(b * KVROWS + s_r) * ks + h * HD_ + s_c4;
  const __bf16* Vb = V + (size_t)(b * KVROWS + s_r) * ks + h * HD_ + s_c4;

  f32x4_t o0 = (f32x4_t){0.f,0.f,0.f,0.f}, o1 = (f32x4_t){0.f,0.f,0.f,0.f};
  float m = -3.0e38f, l = 0.f;
  const float SCALE = 0.17677669529663689f;
  const int slim = CAUSAL ? (qt + 1) * 128 : KVROWS;

  for (int s0 = 0; s0 < slim; s0 += 64) {
    *(uint2*)&K_lds[s_r][s_c4] = *(const uint2*)(Kb + (size_t)s0 * ks);
    bf16x4_t vv = *(const bf16x4_t*)(Vb + (size_t)s0 * ks);
#pragma unroll
    for (int jj = 0; jj < 4; ++jj) Vt_lds[s_c4 + jj][s_r] = vv[jj];
    __syncthreads();

    f32x4_t sa[4];
#pragma unroll
    for (int c = 0; c < 4; ++c) {
      bf16x8_t kf = *(const bf16x8_t*)&K_lds[c * 16 + ln15][kgrp8];
      sa[c] = __builtin_amdgcn_mfma_f32_16x16x32_bf16(kf, qfrag, (f32x4_t){0.f,0.f,0.f,0.f}, 0, 0, 0);
    }
    float v[16];
#pragma unroll
    for (int c = 0; c < 4; ++c)
#pragma unroll
      for (int r = 0; r < 4; ++r) {
        float s = sa[c][r] * SCALE;
        if (CAUSAL && (s0 + c * 16 + kgrp * 4 + r) > q_glob) s += -1e9f;
        v[c * 4 + r] = s;
      }
    float tmax = v[0];
#pragma unroll
    for (int r = 1; r < 16; ++r) tmax = fmaxf(tmax, v[r]);
    tmax = fmaxf(tmax, __shfl_xor(tmax, 16));
    tmax = fmaxf(tmax, __shfl_xor(tmax, 32));
    float mnew = fmaxf(m, tmax);
    float corr = __expf(m - mnew);

    float lsum = 0.f;
#pragma unroll
    for (int c = 0; c < 4; ++c) {
      bf16x4_t pc;
#pragma unroll
      for (int r = 0; r < 4; ++r) {
        float e = __expf(v[c * 4 + r] - mnew);
        lsum += e;
        pc[r] = (__bf16)e;
      }
      *(bf16x4_t*)&P_lds[wv][ln15][c * 16 + kgrp * 4] = pc;
    }
    lsum += __shfl_xor(lsum, 16);
    lsum += __shfl_xor(lsum, 32);
    l = l * corr + lsum;
    m = mnew;

    const float c0 = __shfl(corr, kgrp * 4 + 0);
    const float c1 = __shfl(corr, kgrp * 4 + 1);
    const float c2 = __shfl(corr, kgrp * 4 + 2);
    const float c3 = __shfl(corr, kgrp * 4 + 3);
    o0[0] *= c0; o0[1] *= c1; o0[2] *= c2; o0[3] *= c3;
    o1[0] *= c0; o1[1] *= c1; o1[2] *= c2; o1[3] *= c3;

    bf16x8_t pLo = *(const bf16x8_t*)&P_lds[wv][ln15][kgrp8];
    bf16x8_t pHi = *(const bf16x8_t*)&P_lds[wv][ln15][32 + kgrp8];
    bf16x8_t v0l = *(const bf16x8_t*)&Vt_lds[ln15][kgrp8];
    bf16x8_t v0h = *(const bf16x8_t*)&Vt_lds[ln15][32 + kgrp8];
    bf16x8_t v1l = *(const bf16x8_t*)&Vt_lds[16 + ln15][kgrp8];
    bf16x8_t v1h = *(const bf16x8_t*)&Vt_lds[16 + ln15][32 + kgrp8];
    o0 = __builtin_amdgcn_mfma_f32_16x16x32_bf16(pLo, v0l, o0, 0, 0, 0);
    o0 = __builtin_amdgcn_mfma_f32_16x16x32_bf16(pHi, v0h, o0, 0, 0, 0);
    o1 = __builtin_amdgcn_mfma_f32_16x16x32_bf16(pLo, v1l, o1, 0, 0, 0);
    o1 = __builtin_amdgcn_mfma_f32_16x16x32_bf16(pHi, v1h, o1, 0, 0, 0);
    __syncthreads();
  }

  const float inv = 1.f / l;
  const float i0 = __shfl(inv, kgrp * 4 + 0);
  const float i1 = __shfl(inv, kgrp * 4 + 1);
  const float i2 = __shfl(inv, kgrp * 4 + 2);
  const float i3 = __shfl(inv, kgrp * 4 + 3);
  __bf16* Op = O + (size_t)(b * T_ + qt * 128 + wv * 16 + kgrp * 4) * D_ + h * HD_;
  Op[0 * D_ + ln15] = (__bf16)(o0[0] * i0);  Op[0 * D_ + 16 + ln15] = (__bf16)(o1[0] * i0);
  Op[1 * D_ + ln15] = (__bf16)(o0[1] * i1);  Op[1 * D_ + 16 + ln15] = (__bf16)(o1[1] * i1);
  Op[2 * D_ + ln15] = (__bf16)(o0[2] * i2);  Op[2 * D_ + 16 + ln15] = (__bf16)(o1[2] * i2);
  Op[3 * D_ + ln15] = (__bf16)(o0[3] * i3);  Op[3 * D_ + 16 + ln15] = (__bf16)(o1[3] * i3);
}

// ---------------- final matvec: out = h(BTx128) @ Wp2(128x1) + bp2 -----------
__global__ __launch_bounds__(256)
void head2_kernel(const float* __restrict__ hb, const float* __restrict__ w,
                  const float* __restrict__ bias, float* __restrict__ out) {
  const int row = blockIdx.x * 4 + (threadIdx.x >> 6);
  const int lane = threadIdx.x & 63;
  float a = hb[(size_t)row * 128 + lane] * w[lane]
          + hb[(size_t)row * 128 + 64 + lane] * w[64 + lane];
#pragma unroll
  for (int off = 32; off; off >>= 1) a += __shfl_xor(a, off);
  if (lane == 0) out[row] = a + bias[0];
}

extern "C" void kernel_launch(void* const* d_in, const int* in_sizes, int n_in,
                              void* d_out, int out_size, void* d_ws, size_t ws_size,
                              hipStream_t stream) {
  const float* tgt    = (const float*)d_in[0];
  const float* memory = (const float*)d_in[1];
  const float* W_emb  = (const float*)d_in[2];
  const float* b_emb  = (const float*)d_in[3];
  const float* W_enc  = (const float*)d_in[4];
  const float* b_enc  = (const float*)d_in[5];
  const float* Wq_s = (const float*)d_in[6];  const float* bq_s = (const float*)d_in[7];
  const float* Wk_s = (const float*)d_in[8];  const float* bk_s = (const float*)d_in[9];
  const float* Wv_s = (const float*)d_in[10]; const float* bv_s = (const float*)d_in[11];
  const float* Wo_s = (const float*)d_in[12]; const float* bo_s = (const float*)d_in[13];
  const float* Wq_c = (const float*)d_in[14]; const float* bq_c = (const float*)d_in[15];
  const float* Wk_c = (const float*)d_in[16]; const float* bk_c = (const float*)d_in[17];
  const float* Wv_c = (const float*)d_in[18]; const float* bv_c = (const float*)d_in[19];
  const float* Wo_c = (const float*)d_in[20]; const float* bo_c = (const float*)d_in[21];
  const float* g1  = (const float*)d_in[22]; const float* be1 = (const float*)d_in[23];
  const float* g2  = (const float*)d_in[24]; const float* be2 = (const float*)d_in[25];
  const float* g3  = (const float*)d_in[26]; const float* be3 = (const float*)d_in[27];
  const float* Wf1 = (const float*)d_in[28]; const float* bf1 = (const float*)d_in[29];
  const float* Wf2 = (const float*)d_in[30]; const float* bf2 = (const float*)d_in[31];
  const float* Wp1 = (const float*)d_in[32]; const float* bp1 = (const float*)d_in[33];
  const float* Wp2 = (const float*)d_in[34]; const float* bp2 = (const float*)d_in[35];

  // ---- workspace layout (float units), ~141 MB, disjoint hot buffers ----
  float*  x     = (float*)d_ws;                             // 4,194,304 f
  __bf16* xbf   = (__bf16*)(x + (size_t)4194304);           // 2,097,152 f
  __bf16* membf = xbf + (size_t)4194304;                    // 1,048,576 f
  __bf16* wt    = (__bf16*)((float*)membf + 1048576);       // 2,211,840 f
  float*  bcat  = (float*)(wt + 4423680);                   // 8,192 f
  __bf16* kvall = (__bf16*)(bcat + 8192);                   // 8,388,608 f (8192x2048)
  __bf16* qkv   = kvall + (size_t)16777216;                 // 6,291,456 f (16384x768)
  __bf16* ff    = qkv + (size_t)12582912;                   // 8,388,608 f (16384x1024)
  __bf16* qc    = ff + (size_t)16777216;                    // 2,097,152 f (16384x256)
  __bf16* ao    = qc + (size_t)4194304;                     // 2,097,152 f (16384x256)
  // aliases (phase-disjoint):
  __bf16* memb = ff;                                        // BS*ED bf16 (pre-layer only)
  float*  hbuf = (float*)qc;                                // BT*128 f32 (head phase)

  const size_t o_enc  = 0;
  const size_t o_qkv  = 196608;
  const size_t o_qcw  = 983040;
  const size_t o_kvw  = 1245184;
  const size_t o_os   = 1769472;
  const size_t o_oc   = 2031616;
  const size_t o_f1   = 2293760;
  const size_t o_f2   = 3342336;
  const size_t o_p1   = 4390912;

  TDs td;
  td.d[0]  = {W_enc, o_enc,           ED_, D_,  1, 0};
  td.d[1]  = {Wq_s,  o_qkv + 0,       D_,  D_,  L_, 196608};
  td.d[2]  = {Wk_s,  o_qkv + 65536,   D_,  D_,  L_, 196608};
  td.d[3]  = {Wv_s,  o_qkv + 131072,  D_,  D_,  L_, 196608};
  td.d[4]  = {Wq_c,  o_qcw,           D_,  D_,  L_, 65536};
  td.d[5]  = {Wk_c,  o_kvw + 0,       D_,  D_,  L_, 131072};
  td.d[6]  = {Wv_c,  o_kvw + 65536,   D_,  D_,  L_, 131072};
  td.d[7]  = {Wo_s,  o_os,            D_,  D_,  L_, 65536};
  td.d[8]  = {Wo_c,  o_oc,            D_,  D_,  L_, 65536};
  td.d[9]  = {Wf1,   o_f1,            D_,  FF_, L_, 262144};
  td.d[10] = {Wf2,   o_f2,            FF_, D_,  L_, 262144};
  td.d[11] = {Wp1,   o_p1,            D_,  128, 1, 0};

  dim3 blk(256);
  cvt_bf16_kernel<<<BS_ * ED_ / 1024, blk, 0, stream>>>(memory, memb);
  transpose_cvt_kernel<<<dim3(1024, 12), blk, 0, stream>>>(td, wt);
  bias_concat_kernel<<<20, blk, 0, stream>>>(bq_s, bk_s, bv_s, bk_c, bv_c, bcat);
  embed_kernel<<<BT_ * D_ / 256, blk, 0, stream>>>(tgt, W_emb, b_emb, x, xbf);

  const float* bqkv = bcat;            // [L][768]
  const float* bkv  = bcat + 3072;     // [L*512] linear
  const dim3 gA(B_ * H_, T_ / 128);

  // encoder proj: memb(8192x768) -> membf(8192x256)
  gemm_bf<0,1><<<64 * 4, blk, 0, stream>>>(memb, wt + o_enc, b_enc, membf, D_, ED_, 4, 8);
  // ALL layers' cross-KV: membf @ [2048x256]^T -> kvall(8192x2048)
  gemm_bf2<0,1><<<64 * 16, blk, 0, stream>>>(membf, wt + o_kvw, bkv, kvall, 2048, D_, 16, 8);
  // layer-0 QKV
  gemm_bf2<0,1><<<128 * 6, blk, 0, stream>>>(xbf, wt + o_qkv, bqkv, qkv, 768, D_, 6, 16);

  for (int i = 0; i < L_; ++i) {
    // ---- self attention + [O-proj + LN1 + cross-Q] ----
    attn_mfma<true><<<gA, dim3(512), 0, stream>>>(qkv, qkv + 256, qkv + 512, ao, T_, 768, 768);
    gemm_ln_next<256,0,0><<<512, blk, 0, stream>>>(
        ao, wt + o_os + (size_t)i * 65536, bo_s + i * D_, g1 + i * D_, be1 + i * D_,
        x, xbf, D_, 64, wt + o_qcw + (size_t)i * 65536, bq_c + i * D_, qc);
    // ---- cross attention + [O-proj + LN2 (writes xbf)] + standalone FF1 ----
    attn_mfma<false><<<gA, dim3(512), 0, stream>>>(qc, kvall + i * 512, kvall + i * 512 + 256, ao, S_, 256, 2048);
    gemm_ln_next<0,0,1><<<512, blk, 0, stream>>>(
        ao, wt + o_oc + (size_t)i * 65536, bo_c + i * D_, g2 + i * D_, be2 + i * D_,
        x, xbf, D_, 64, (const __bf16*)nullptr, (const float*)nullptr, (__bf16*)nullptr);
    gemm_bf2<1,1><<<128 * 8, blk, 0, stream>>>(xbf, wt + o_f1 + (size_t)i * 262144, bf1 + i * FF_, ff, FF_, D_, 8, 16);
    // ---- FF2 + LN3 + [next-layer QKV] ----
    if (i < L_ - 1) {
      gemm_ln_next<768,0,0><<<512, blk, 0, stream>>>(
          ff, wt + o_f2 + (size_t)i * 262144, bf2 + i * D_, g3 + i * D_, be3 + i * D_,
          x, xbf, FF_, 64, wt + o_qkv + (size_t)(i + 1) * 196608, bqkv + (i + 1) * 768, qkv);
    } else {
      gemm_ln_next<0,0,1><<<512, blk, 0, stream>>>(
          ff, wt + o_f2 + (size_t)i * 262144, bf2 + i * D_, g3 + i * D_, be3 + i * D_,
          x, xbf, FF_, 64, (const __bf16*)nullptr, (const float*)nullptr, (__bf16*)nullptr);
    }
  }
  // ---- head ----
  gemm_bf<1,0><<<128 * 2, blk, 0, stream>>>(xbf, wt + o_p1, bp1, hbuf, 128, D_, 2, 16);
  head2_kernel<<<BT_ / 4, blk, 0, stream>>>(hbuf, Wp2, bp2, (float*)d_out);
}